// Round 12
// baseline (759.767 us; speedup 1.0000x reference)
//
#include <hip/hip_runtime.h>

typedef float f32x4 __attribute__((ext_vector_type(4)));
typedef float v4f  __attribute__((ext_vector_type(4)));
typedef _Float16 half8 __attribute__((ext_vector_type(8)));
typedef unsigned int u32;
typedef unsigned short u16;

#define HH 30
#define DIN 4
#define DOUT 4
#define NB 16      // batch elements per block
#define L2E 1.44269504088896340736f

#if __has_builtin(__builtin_amdgcn_exp2f)
#define EXP2F(v) __builtin_amdgcn_exp2f(v)
#else
#define EXP2F(v) exp2f(v)
#endif

// Pre-scaled sigmoid: -log2e (g rows: -2*log2e) folded into W and bias.
__device__ __forceinline__ float sig2f(float v) {
    return __builtin_amdgcn_rcpf(1.0f + EXP2F(v));
}

__device__ __forceinline__ f32x4 MF(half8 a, half8 b, f32x4 c) {
    return __builtin_amdgcn_mfma_f32_16x16x32_f16(a, b, c, 0, 0, 0);
}

union F8 { half8 h; _Float16 e[8]; u32 w[4]; };
union HU { _Float16 h; u16 s; };

// Workgroup barrier with LGKM-only drain (no vmcnt): cross-wave correctness
// only involves LDS; outstanding global x-prefetches stay in flight.
__device__ __forceinline__ void lds_barrier() {
    __builtin_amdgcn_sched_barrier(0);
    asm volatile("s_waitcnt lgkmcnt(0)" ::: "memory");
    __builtin_amdgcn_sched_barrier(0);
    __builtin_amdgcn_s_barrier();
    __builtin_amdgcn_sched_barrier(0);
}

// Layer-pipelined MFMA LSTM, 8-WAVE version. One block = 8 waves = 16 elems.
// Waves 0-3 ("L1"): h1(s) at slot s, tiles {2w, 2w+1}.
// Waves 4-7 ("L2"): h2(s-1) at slot s, tiles {2(w-4), 2(w-4)+1}; head
//                   out(s-2) round-robin (w == 4+(s&3)).
// RATIONALE (R11 post-mortem): slot wall was DS-pipe burst serialization —
// 16 waves x 3 avg ds_read_b128 after each barrier. B-operand reads are
// per-WAVE not per-tile (same h feeds both tiles), so 2 tiles/wave halves
// the read burst 48 -> 24 b128/slot while keeping the split-chain structure
// and BIT-IDENTICAL arithmetic (absmax must equal R11's 0.002441406).
// SIMD placement w%4: each SIMD gets exactly 1 L1 + 1 L2 wave.
// Everything else as R11: frag-layout u16 LDS planes, parity double-buffer,
// ONE lgkm-only barrier/slot, gx = Wih1@x + b1 in exact f32 one slot ahead.
__global__ __launch_bounds__(512)
void lstm2_kernel(const float* __restrict__ x,
                  const float* __restrict__ Wih1, const float* __restrict__ bih1,
                  const float* __restrict__ Whh1, const float* __restrict__ bhh1,
                  const float* __restrict__ Wih2, const float* __restrict__ bih2,
                  const float* __restrict__ Whh2, const float* __restrict__ bhh2,
                  const float* __restrict__ Wlin, const float* __restrict__ blin,
                  float* __restrict__ out, int T)
{
    const int tid = threadIdx.x;
    const int w = tid >> 6;        // wave 0..7
    const int wg = w & 3;          // tile-pair index within layer group
    const bool isL2 = (w >= 4);
    const int l = tid & 63;
    const int n = l & 15;          // elem col / A-row-in-tile
    const int p = l >> 4;          // quad index
    const int b0 = blockIdx.x * NB;
    const float M2 = -2.0f * L2E;  // tanh(c) = 2*sig2f(M2*c)-1

    // [buf][plane: 0=h1hi 1=h1lo 2=h2hi 3=h2lo][n][pos], stride 40 u16
    __shared__ __align__(16) u16 lds[2][4][16][40];
    {
        u32* z = reinterpret_cast<u32*>(&lds[0][0][0][0]);
        const int tot = 2 * 4 * 16 * 40 / 2;
        for (int i = tid; i < tot; i += 512) z[i] = 0u;
    }

    // ---------- per-lane constants, PER TILE (ri = 0,1) ----------
    const int gA = n & 3;                       // gate of this A row
    const float scA = (gA == 2) ? -2.0f * L2E : -L2E;

    half8 wA_h0[2], wA_l0[2], wA_h1[2], wA_l1[2];
    f32x4 biasf[2];
    int pos_[2];
    bool okq_[2];
    int kqc_[2];

#pragma unroll
    for (int ri = 0; ri < 2; ++ri) {
        const int rt = 2 * wg + ri;             // row-tile 0..7
        const int qA = 4 * rt + (n >> 2);       // h-row of this A row
        const int kq = 4 * rt + p;              // this lane's C-frag h-row
        okq_[ri] = (kq < HH);
        kqc_[ri] = okq_[ri] ? kq : 0;
        pos_[ri] = ((kq & 15) >> 2) * 8 + (kq >> 4) * 4 + (kq & 3);

        F8 H0, L0, H1, L1v;
#pragma unroll
        for (int e = 0; e < 8; ++e) {
            const int k = 16 * (e >> 2) + 4 * p + (e & 3);
            const bool kok = (qA < HH && k < HH);
            float v0, v1;
            if (isL2) {
                v0 = kok ? Wih2[(gA * HH + qA) * HH + k] * scA : 0.0f;
                v1 = kok ? Whh2[(gA * HH + qA) * HH + k] * scA : 0.0f;
            } else {
                v0 = kok ? Whh1[(gA * HH + qA) * HH + k] * scA : 0.0f;
                v1 = 0.0f;
            }
            _Float16 t0 = (_Float16)v0, t1 = (_Float16)v1;
            H0.e[e] = t0; L0.e[e] = (_Float16)(v0 - (float)t0);
            H1.e[e] = t1; L1v.e[e] = (_Float16)(v1 - (float)t1);
        }
        wA_h0[ri] = H0.h; wA_l0[ri] = L0.h;
        wA_h1[ri] = H1.h; wA_l1[ri] = L1v.h;

#pragma unroll
        for (int r = 0; r < 4; ++r) {
            const float scr = (r == 2) ? -2.0f * L2E : -L2E;
            const float bv = isL2
                ? (bih2[r * HH + kqc_[ri]] + bhh2[r * HH + kqc_[ri]])
                : (bih1[r * HH + kqc_[ri]] + bhh1[r * HH + kqc_[ri]]);
            biasf[ri][r] = okq_[ri] ? bv * scr : 0.0f;
        }
    }

    // L1: per-lane x weights (exact f32), per tile, 4 gates x DIN
    float wxs[2][4][DIN];
#pragma unroll
    for (int ri = 0; ri < 2; ++ri)
#pragma unroll
        for (int r = 0; r < 4; ++r) {
            const float scr = (r == 2) ? -2.0f * L2E : -L2E;
#pragma unroll
            for (int c = 0; c < DIN; ++c)
                wxs[ri][r][c] = (!isL2 && okq_[ri])
                    ? Wih1[(r * HH + kqc_[ri]) * DIN + c] * scr : 0.0f;
        }

    // head frags (L2 waves only use them)
    half8 alin_h, alin_l;
    f32x4 blinf;
    {
        F8 Lh, Ll;
#pragma unroll
        for (int e = 0; e < 8; ++e) {
            const int k = 16 * (e >> 2) + 4 * p + (e & 3);
            float v = (isL2 && n < DOUT && k < HH) ? Wlin[n * HH + k] : 0.0f;
            _Float16 t16 = (_Float16)v;
            Lh.e[e] = t16; Ll.e[e] = (_Float16)(v - (float)t16);
        }
        alin_h = Lh.h; alin_l = Ll.h;
#pragma unroll
        for (int r = 0; r < 4; ++r)
            blinf[r] = (p == 0) ? blin[r] : 0.0f;
    }

    float cst0 = 0.0f, cst1 = 0.0f;            // c-state per tile
    half8 bh1_h = {}, bh1_l = {}, bh2_h = {}, bh2_l = {};   // h(-1)=0

    const v4f* xp = reinterpret_cast<const v4f*>(x) + (size_t)(b0 + n) * T;

    // gx pipeline (L1 only): gx[ri] = Wih1@x(s) + bias1 (exact f32)
    f32x4 gx0 = biasf[0], gx1 = biasf[1];
    v4f xn = {};
    if (!isL2) {
        const v4f x0 = xp[0];
#pragma unroll
        for (int r = 0; r < 4; ++r)
#pragma unroll
            for (int c = 0; c < DIN; ++c) {
                gx0[r] = fmaf(wxs[0][r][c], x0[c], gx0[r]);
                gx1[r] = fmaf(wxs[1][r][c], x0[c], gx1[r]);
            }
        xn = xp[(T > 1) ? 1 : 0];
    }

    __syncthreads();   // zero-init visible

    const f32x4 zf = {0.0f, 0.0f, 0.0f, 0.0f};
    const int TS = T + 2;

    for (int s = 0; s < TS; ++s) {
        if (!isL2) {
            // ---- L1: h1(s) = act(Whh1 @ h1(s-1) + gx(s)), 2 tiles ----
#pragma unroll
            for (int ri = 0; ri < 2; ++ri) {
                const f32x4 gxc = ri ? gx1 : gx0;
                f32x4 a = MF(wA_h0[ri], bh1_h, gxc);
                f32x4 b = MF(wA_h0[ri], bh1_l, zf);
                f32x4 c = MF(wA_l0[ri], bh1_h, zf);
                const f32x4 g = (a + b) + c;

                const float iv = sig2f(g[0]);
                const float fv = sig2f(g[1]);
                const float gg = fmaf(2.0f, sig2f(g[2]), -1.0f);
                const float ov = sig2f(g[3]);
                float& cs = ri ? cst1 : cst0;
                cs = fmaf(fv, cs, iv * gg);
                const float r = sig2f(M2 * cs);
                const float hn = fmaf(2.0f * ov, r, -ov);   // o*tanh(c)

                HU hi, lo;
                hi.h = (_Float16)hn;
                lo.h = (_Float16)(hn - (float)hi.h);
                lds[s & 1][0][n][pos_[ri]] = okq_[ri] ? hi.s : (u16)0;
                lds[s & 1][1][n][pos_[ri]] = okq_[ri] ? lo.s : (u16)0;
            }
        } else {
            if (s >= 1) {
                // ---- L2: h2(s-1) = act(Wih2@h1(s-1)+Whh2@h2(s-2)+b2) ----
#pragma unroll
                for (int ri = 0; ri < 2; ++ri) {
                    f32x4 a = MF(wA_h0[ri], bh1_h, biasf[ri]);
                    f32x4 b = MF(wA_h0[ri], bh1_l, zf);
                    f32x4 c = MF(wA_l0[ri], bh1_h, zf);
                    f32x4 d = MF(wA_h1[ri], bh2_h, zf);
                    f32x4 e = MF(wA_h1[ri], bh2_l, zf);
                    f32x4 f = MF(wA_l1[ri], bh2_h, zf);
                    const f32x4 g = ((a + b) + (c + d)) + (e + f);

                    const float iv = sig2f(g[0]);
                    const float fv = sig2f(g[1]);
                    const float gg = fmaf(2.0f, sig2f(g[2]), -1.0f);
                    const float ov = sig2f(g[3]);
                    float& cs = ri ? cst1 : cst0;
                    cs = fmaf(fv, cs, iv * gg);
                    const float r = sig2f(M2 * cs);
                    const float hn = fmaf(2.0f * ov, r, -ov);

                    HU hi, lo;
                    hi.h = (_Float16)hn;
                    lo.h = (_Float16)(hn - (float)hi.h);
                    lds[(s + 1) & 1][2][n][pos_[ri]] = okq_[ri] ? hi.s : (u16)0;
                    lds[(s + 1) & 1][3][n][pos_[ri]] = okq_[ri] ? lo.s : (u16)0;
                }
            }
            // ---- head: out(s-2) = Wlin @ h2(s-2) + blin (round-robin) ----
            if (s >= 2 && w == 4 + (s & 3)) {
                f32x4 oh = blinf;                 // bh2 regs = h2(s-2)
                oh = MF(alin_h, bh2_h, oh);
                oh = MF(alin_h, bh2_l, oh);
                oh = MF(alin_l, bh2_h, oh);
                if (p == 0) {
                    v4f ov4;
                    ov4.x = oh[0]; ov4.y = oh[1]; ov4.z = oh[2]; ov4.w = oh[3];
                    *reinterpret_cast<v4f*>(
                        out + (((size_t)(b0 + n)) * T + (s - 2)) * DOUT) = ov4;
                }
            }
        }

        lds_barrier();   // lgkm-only drain + s_barrier

        // reads for slot s+1 (per WAVE, not per tile — the halved burst):
        // h1(s) @ buf[s&1]; h2(s-1) @ buf[(s+1)&1]
        bh1_h = *reinterpret_cast<const half8*>(&lds[s & 1][0][n][8 * p]);
        bh1_l = *reinterpret_cast<const half8*>(&lds[s & 1][1][n][8 * p]);
        if (isL2) {
            bh2_h = *reinterpret_cast<const half8*>(&lds[(s + 1) & 1][2][n][8 * p]);
            bh2_l = *reinterpret_cast<const half8*>(&lds[(s + 1) & 1][3][n][8 * p]);
        } else {
            // off-path: gx(s+1) from xn, then prefetch x(s+2)
            f32x4 g0 = biasf[0], g1 = biasf[1];
#pragma unroll
            for (int r = 0; r < 4; ++r)
#pragma unroll
                for (int c = 0; c < DIN; ++c) {
                    g0[r] = fmaf(wxs[0][r][c], xn[c], g0[r]);
                    g1[r] = fmaf(wxs[1][r][c], xn[c], g1[r]);
                }
            gx0 = g0; gx1 = g1;
            xn = xp[(s + 2 < T) ? (s + 2) : (T - 1)];
        }
    }
}

extern "C" void kernel_launch(void* const* d_in, const int* in_sizes, int n_in,
                              void* d_out, int out_size, void* d_ws, size_t ws_size,
                              hipStream_t stream)
{
    const float* x    = (const float*)d_in[0];
    const float* Wih1 = (const float*)d_in[1];
    const float* bih1 = (const float*)d_in[2];
    const float* Whh1 = (const float*)d_in[3];
    const float* bhh1 = (const float*)d_in[4];
    const float* Wih2 = (const float*)d_in[5];
    const float* bih2 = (const float*)d_in[6];
    const float* Whh2 = (const float*)d_in[7];
    const float* bhh2 = (const float*)d_in[8];
    const float* Wlin = (const float*)d_in[9];
    const float* blin = (const float*)d_in[10];
    float* out = (float*)d_out;

    const int T = 1024;
    const int B = in_sizes[0] / (T * DIN);   // 2048

    hipLaunchKernelGGL(lstm2_kernel, dim3(B / NB), dim3(512), 0, stream,
                       x, Wih1, bih1, Whh1, bhh1, Wih2, bih2, Whh2, bhh2,
                       Wlin, blin, out, T);
}